// Round 5
// baseline (8117.351 us; speedup 1.0000x reference)
//
#include <hip/hip_runtime.h>
#include <math.h>

// ModalityRouter: logits = x @ gate_w^T (M=32768, K=2048, N=64),
// top-2 -> softmax -> gates/indices/load/top_logits.
//
// Round-2 design (3rd resubmit; rounds 2-4 hit GPUAcquisitionTimeout):
// lane=expert, x via LDS broadcast (vector path), w per-lane.
//  - x tile [32 tok][128 k] double-buffered in LDS, staged with coalesced
//    float4 loads + ds_write_b128 (NO scalar loads of x -- round 1's 24%
//    VALUBusy was s_load-from-HBM latency).
//  - inner loop: uniform-address ds_read_b128 (broadcast, conflict-free)
//    feeds 4 v_fmac_f32 per read; w chunk preloaded to VGPRs per half-chunk.
//  - each wave owns 8 tokens exclusively -> no cross-wave reduce; top-2 via
//    shfl_xor butterfly (tie -> lowest index, matches lax.top_k).

#define NE       64
#define KD       2048
#define TT       32            // tokens per block
#define NW       4             // waves per block
#define TPW      (TT / NW)     // 8 tokens per wave
#define BK       128           // k per chunk
#define NCHUNK   (KD / BK)     // 16
#define M_TOTAL  32768
#define IDX_OFF  65536
#define LOAD_OFF 131072
#define TL_OFF   131136
#define NEG_INF  -3.0e38f

__global__ __launch_bounds__(256, 4)
void router_kernel(const float* __restrict__ x,
                   const float* __restrict__ gw,
                   float* __restrict__ out)
{
    __shared__ float xs[2][TT][BK];     // 32 KB double-buffered x tile
    __shared__ float sload[NE];

    const int tid  = threadIdx.x;
    const int wave = tid >> 6;
    const int lane = tid & 63;          // expert id
    const long tok0 = (long)blockIdx.x * TT;

    if (tid < NE) sload[tid] = 0.0f;

    // staging map: thread covers elements e = j*1024 + tid*4  (j = 0..3)
    const int e0    = tid * 4;
    const int tok_t = e0 >> 7;          // 0..7   (token within tile, j adds 8)
    const int kk    = e0 & 127;         // k offset within chunk (16B aligned)

    const float* xrow[4];
#pragma unroll
    for (int j = 0; j < 4; ++j)
        xrow[j] = x + (size_t)(tok0 + tok_t + j * 8) * KD + kk;

    float acc[TPW];
#pragma unroll
    for (int t = 0; t < TPW; ++t) acc[t] = 0.0f;

    const float* wl   = gw + (size_t)lane * KD;   // per-lane expert row
    const int    wtok = wave * TPW;

    // prologue: stage chunk 0 into buffer 0
    {
        float4 st[4];
#pragma unroll
        for (int j = 0; j < 4; ++j)
            st[j] = *reinterpret_cast<const float4*>(xrow[j]);
#pragma unroll
        for (int j = 0; j < 4; ++j)
            *reinterpret_cast<float4*>(&xs[0][tok_t + j * 8][kk]) = st[j];
    }
    __syncthreads();

    for (int c = 0; c < NCHUNK; ++c) {
        const int b = c & 1;

        // issue next chunk's global loads early (latency hides under FMAs)
        float4 st[4];
        if (c + 1 < NCHUNK) {
#pragma unroll
            for (int j = 0; j < 4; ++j)
                st[j] = *reinterpret_cast<const float4*>(xrow[j] + (size_t)(c + 1) * BK);
        }

        // compute: 2 halves x 16 quads; w preloaded per half (64 VGPRs)
#pragma unroll
        for (int h = 0; h < 2; ++h) {
            float4 wv[16];
#pragma unroll
            for (int q = 0; q < 16; ++q)
                wv[q] = *reinterpret_cast<const float4*>(wl + c * BK + h * 64 + q * 4);
#pragma unroll
            for (int q = 0; q < 16; ++q) {
#pragma unroll
                for (int t = 0; t < TPW; ++t) {
                    const float4 xv = *reinterpret_cast<const float4*>(
                        &xs[b][wtok + t][h * 64 + q * 4]);   // uniform -> broadcast
                    acc[t] = fmaf(xv.x, wv[q].x, acc[t]);
                    acc[t] = fmaf(xv.y, wv[q].y, acc[t]);
                    acc[t] = fmaf(xv.z, wv[q].z, acc[t]);
                    acc[t] = fmaf(xv.w, wv[q].w, acc[t]);
                }
            }
        }

        // write staged regs into the other buffer, then barrier
        if (c + 1 < NCHUNK) {
            const int nb = (c + 1) & 1;
#pragma unroll
            for (int j = 0; j < 4; ++j)
                *reinterpret_cast<float4*>(&xs[nb][tok_t + j * 8][kk]) = st[j];
        }
        __syncthreads();
    }

    // epilogue: per-token top-2 across lanes (lane = expert)
#pragma unroll
    for (int t = 0; t < TPW; ++t) {
        const float v = acc[t];

        float bv = v; int bi = lane;
#pragma unroll
        for (int off = 32; off >= 1; off >>= 1) {
            const float ov = __shfl_xor(bv, off);
            const int   oi = __shfl_xor(bi, off);
            if (ov > bv || (ov == bv && oi < bi)) { bv = ov; bi = oi; }
        }

        float cv = (lane == bi) ? NEG_INF : v; int ci = lane;
#pragma unroll
        for (int off = 32; off >= 1; off >>= 1) {
            const float ov = __shfl_xor(cv, off);
            const int   oi = __shfl_xor(ci, off);
            if (ov > cv || (ov == cv && oi < ci)) { cv = ov; ci = oi; }
        }

        if (lane == t) {
            const size_t gt = (size_t)(tok0 + wtok + t);
            const float g1 = 1.0f / (1.0f + expf(bv - cv));  // e^{v1}/(e^{v0}+e^{v1})
            const float g0 = 1.0f - g1;
            out[gt * 2 + 0] = g0;
            out[gt * 2 + 1] = g1;
            out[IDX_OFF + gt * 2 + 0] = (float)bi;
            out[IDX_OFF + gt * 2 + 1] = (float)ci;
            out[TL_OFF + gt * 2 + 0] = bv;
            out[TL_OFF + gt * 2 + 1] = cv;
            atomicAdd(&sload[bi], g0);
            atomicAdd(&sload[ci], g1);
        }
    }
    __syncthreads();
    if (tid < NE) atomicAdd(out + LOAD_OFF + tid, sload[tid]);
}

extern "C" void kernel_launch(void* const* d_in, const int* in_sizes, int n_in,
                              void* d_out, int out_size, void* d_ws, size_t ws_size,
                              hipStream_t stream)
{
    const float* x  = (const float*)d_in[0];
    const float* gw = (const float*)d_in[1];
    float* out = (float*)d_out;

    hipMemsetAsync(out + LOAD_OFF, 0, NE * sizeof(float), stream);
    router_kernel<<<dim3(M_TOTAL / TT), dim3(256), 0, stream>>>(x, gw, out);
}